// Round 4
// baseline (307.483 us; speedup 1.0000x reference)
//
#include <hip/hip_runtime.h>

#define K_CODES 512
#define DIM 64
#define HW 1024
#define NVEC 65536

// Output offsets (flat concat, reference return order)
#define O0 0             // loss (1)
#define O1 1             // out_q NCHW (4194304)  -- also used as xT scratch between k1 and k_q
#define O2 4194305       // perplexity (1)
#define O3 4194306       // idx as float (65536)
#define O4 4259842       // new_cs (512)
#define O5 4260354       // new_ema_w (32768)
#define O6 4293122       // new_embedding (32768)

// ws float-offset layout (~600 KB total)
#define WS_LOSS 0        // 512 per-block loss partials
#define WS_CNT  512      // 512 counts (float)
#define WS_EE   1024     // 512 ||e||^2
#define WS_IDX  1536     // 65536 int idx
#define WS_DW   67072    // 32768 dw
#define WS_BP   99840    // 98304 bf16 B-pack (MFMA-frag order)
#define XSS     65       // odd LDS row stride -> <=2-way bank aliasing

typedef __bf16 bf16x8 __attribute__((ext_vector_type(8)));
typedef float  f32x4  __attribute__((ext_vector_type(4)));
typedef float  f32x4v __attribute__((ext_vector_type(4)));

__global__ void k0_init(const float* __restrict__ emb, float* __restrict__ wsf) {
    const int b = blockIdx.x, t = threadIdx.x;
    if (b < 2) {
        int k = b * 256 + t;                             // 0..511
        const float* e = emb + k * DIM;
        float s = 0.0f;
        #pragma unroll
        for (int c = 0; c < DIM; ++c) s += e[c] * e[c];
        wsf[WS_EE + k] = s;                              // ||e_k||^2
    } else {
        // Pack bf16 3-way split of (-2*e) into MFMA B-fragment order:
        // frag(s, ntg, ks): lane l holds B^T[code = ntg*16 + (l&15)][c = ks*32 + (l>>4)*8 + j]
        int g = (b - 2) * 256 + t;                       // 0..98303
        int j    = g & 7;
        int lane = (g >> 3) & 63;
        int ks   = (g >> 9) & 1;
        int rest = g >> 10;                              // 0..95
        int ntg  = rest & 31;
        int s    = rest >> 5;                            // split 0..2
        int code = ntg * 16 + (lane & 15);
        int c    = ks * 32 + (lane >> 4) * 8 + j;
        float v = -2.0f * emb[code * DIM + c];
        __bf16 h0 = (__bf16)v;  float r1 = v  - (float)h0;
        __bf16 h1 = (__bf16)r1; float r2 = r1 - (float)h1;
        __bf16 hv = (s == 0) ? h0 : (s == 1 ? h1 : (__bf16)r2);
        ((__bf16*)(wsf + WS_BP))[g] = hv;
    }
}

// Block: 512 threads = 8 waves; 128 vectors x 512 codes per block.
// GEMM + argmin ONLY. No atomics. Writes idx, loss partial, xT rows (to O1 scratch).
__global__ __launch_bounds__(512, 2)
void k1_main(const float* __restrict__ in, const float* __restrict__ emb,
             float* __restrict__ out, float* __restrict__ wsf) {
    __shared__ float xs[128 * XSS];     // fp32 x tile, row=vector, col=c
    __shared__ float pmin[4][128];
    __shared__ int   pidx[4][128];
    __shared__ float xxs[128];
    __shared__ float lossp[2];

    const int t    = threadIdx.x;
    const int lane = t & 63;
    const int wave = t >> 6;           // 0..7
    const int mi2  = wave & 1;         // m half (64 vectors)
    const int ni2  = wave >> 1;        // n quarter (128 codes)
    const int col  = lane & 15;
    const int quad = lane >> 4;

    const int blk     = blockIdx.x;
    const int n_img   = blk >> 3;
    const int hw_base = (blk & 7) * 128;
    const float* xbase = in + n_img * (DIM * HW) + hw_base;

    // Stage x: 128 vectors x 64 c, coalesced global reads; stride-65 LDS (conflict-free)
    #pragma unroll
    for (int rep = 0; rep < 16; ++rep) {
        int e = rep * 512 + t;
        int c = e >> 7, h0 = e & 127;
        xs[h0 * XSS + c] = xbase[c * HW + h0];
    }

    // Accumulators init with ||e||^2 (d = ee - 2<x,e>)
    f32x4 acc[4][8];
    #pragma unroll
    for (int nt = 0; nt < 8; ++nt) {
        float eev = wsf[WS_EE + ni2 * 128 + nt * 16 + col];
        #pragma unroll
        for (int mi = 0; mi < 4; ++mi) {
            acc[mi][nt][0] = eev; acc[mi][nt][1] = eev;
            acc[mi][nt][2] = eev; acc[mi][nt][3] = eev;
        }
    }

    __syncthreads();

    // ||x||^2 per vector (loss only)
    if (t < 128) {
        float s = 0.0f;
        #pragma unroll
        for (int c = 0; c < DIM; ++c) { float v = xs[t * XSS + c]; s += v * v; }
        xxs[t] = s;
    }

    const bf16x8* bp8 = (const bf16x8*)(wsf + WS_BP);

    // K-loop: 2 k-steps x 6 split-pairs {(0,0),(1,0),(2,0),(0,1),(1,1),(0,2)}
    #pragma unroll
    for (int ks = 0; ks < 2; ++ks) {
        bf16x8 A0[4], A1[4], A2[4];
        #pragma unroll
        for (int mi = 0; mi < 4; ++mi) {
            const float* src = &xs[(mi2 * 64 + mi * 16 + col) * XSS + ks * 32 + quad * 8];
            #pragma unroll
            for (int j = 0; j < 8; ++j) {
                float v = src[j];
                __bf16 h0 = (__bf16)v;  float r1 = v  - (float)h0;
                __bf16 h1 = (__bf16)r1; float r2 = r1 - (float)h1;
                A0[mi][j] = h0; A1[mi][j] = h1; A2[mi][j] = (__bf16)r2;
            }
        }
        #pragma unroll
        for (int s = 0; s < 3; ++s) {
            bf16x8 Bv[8];
            #pragma unroll
            for (int nt = 0; nt < 8; ++nt)
                Bv[nt] = bp8[(((s * 32 + ni2 * 8 + nt) * 2 + ks) * 64) + lane];
            #pragma unroll
            for (int mi = 0; mi < 4; ++mi)
                #pragma unroll
                for (int nt = 0; nt < 8; ++nt)
                    acc[mi][nt] = __builtin_amdgcn_mfma_f32_16x16x32_bf16(A0[mi], Bv[nt], acc[mi][nt], 0, 0, 0);
            if (s < 2) {
                #pragma unroll
                for (int mi = 0; mi < 4; ++mi)
                    #pragma unroll
                    for (int nt = 0; nt < 8; ++nt)
                        acc[mi][nt] = __builtin_amdgcn_mfma_f32_16x16x32_bf16(A1[mi], Bv[nt], acc[mi][nt], 0, 0, 0);
            }
            if (s == 0) {
                #pragma unroll
                for (int mi = 0; mi < 4; ++mi)
                    #pragma unroll
                    for (int nt = 0; nt < 8; ++nt)
                        acc[mi][nt] = __builtin_amdgcn_mfma_f32_16x16x32_bf16(A2[mi], Bv[nt], acc[mi][nt], 0, 0, 0);
            }
        }
    }

    // Argmin. C layout: col(code) = lane&15, row(vector) = quad*4 + reg.
    #pragma unroll
    for (int mi = 0; mi < 4; ++mi) {
        #pragma unroll
        for (int r = 0; r < 4; ++r) {
            float v  = acc[mi][0][r];
            int   bi = ni2 * 128 + col;
            #pragma unroll
            for (int nt = 1; nt < 8; ++nt) {            // ascending codes, strict < = first-min
                float u  = acc[mi][nt][r];
                int   ui = ni2 * 128 + nt * 16 + col;
                if (u < v) { v = u; bi = ui; }
            }
            #pragma unroll
            for (int off = 1; off < 16; off <<= 1) {    // 16-lane butterfly, idx tie-break
                float ov = __shfl_xor(v, off);
                int   oi = __shfl_xor(bi, off);
                if (ov < v || (ov == v && oi < bi)) { v = ov; bi = oi; }
            }
            if (col == 0) {
                int row = mi2 * 64 + mi * 16 + quad * 4 + r;
                pmin[ni2][row] = v;
                pidx[ni2][row] = bi;
            }
        }
    }
    __syncthreads();

    // Combine the 4 n-quarters; write idx (float out + int ws), loss partial
    if (t < 128) {
        float v = pmin[0][t]; int bi = pidx[0][t];
        #pragma unroll
        for (int q = 1; q < 4; ++q) {
            float u = pmin[q][t]; int ui = pidx[q][t];
            if (u < v) { v = u; bi = ui; }
        }
        out[O3 + blk * 128 + t] = (float)bi;
        ((int*)(wsf + WS_IDX))[blk * 128 + t] = bi;
        float ld = v + xxs[t];                           // d_min = xx + (ee - 2<x,e>)
        #pragma unroll
        for (int off = 32; off > 0; off >>= 1) ld += __shfl_down(ld, off);
        if ((t & 63) == 0) lossp[t >> 6] = ld;
    }
    __syncthreads();
    if (t == 0) wsf[WS_LOSS + blk] = lossp[0] + lossp[1];

    // Flush xT rows (vector-major, 64 floats) into O1 scratch -- coalesced
    float* xq = out + O1 + blk * (128 * 64);
    #pragma unroll
    for (int rep = 0; rep < 16; ++rep) {
        int g = rep * 512 + t;
        int row = g >> 6, c = g & 63;
        xq[g] = xs[row * XSS + c];
    }
}

// One block per code: ballot-scan idx, gather matched xT rows, plain-store dw row + count.
__global__ __launch_bounds__(256, 4)
void k_dw(const float* __restrict__ xq, const int* __restrict__ idxw,
          float* __restrict__ wsf) {
    __shared__ float sacc[4][64];
    __shared__ int   scnt[4];
    const int t = threadIdx.x, lane = t & 63, w = t >> 6;
    const int code = blockIdx.x;

    float acc = 0.0f;
    int   cnt = 0;
    const int* ip = idxw + w * 16384;
    #pragma unroll 4
    for (int r = 0; r < 256; ++r) {
        int iv = ip[r * 64 + lane];
        unsigned long long m = __ballot(iv == code);    // wave-uniform
        cnt += (int)__popcll(m);
        while (m) {                                     // uniform loop, no divergence
            int s = __ffsll((long long)m) - 1; m &= m - 1;
            int vid = w * 16384 + r * 64 + s;
            acc += xq[vid * 64 + lane];                 // coalesced 256B row
        }
    }
    sacc[w][lane] = acc;
    if (lane == 0) scnt[w] = cnt;
    __syncthreads();
    if (w == 0) {
        float a = sacc[0][lane] + sacc[1][lane] + sacc[2][lane] + sacc[3][lane];
        wsf[WS_DW + code * 64 + lane] = a;              // exclusive ownership: plain store
        if (lane == 0)
            wsf[WS_CNT + code] = (float)(scnt[0] + scnt[1] + scnt[2] + scnt[3]);
    }
}

// Regenerate out_q into O1 from emb + idx (O1's xT scratch already consumed by k_dw).
__global__ __launch_bounds__(256, 4)
void k_q(const float* __restrict__ emb, const int* __restrict__ idxw,
         float* __restrict__ out) {
    const int t    = threadIdx.x;
    const int lane = t & 63;
    const int cg   = t >> 6;                 // c-group 0..3 (16 channels each)
    const int b    = blockIdx.x;
    const int n    = b >> 4;
    const int hw0  = (b & 15) * 64;

    int iv = idxw[n * HW + hw0 + lane];
    const f32x4v* er = (const f32x4v*)(emb + iv * DIM + cg * 16);   // 64B row chunk
    f32x4v e0 = er[0], e1 = er[1], e2 = er[2], e3 = er[3];
    float ev[16];
    #pragma unroll
    for (int j = 0; j < 4; ++j) { ev[j] = e0[j]; ev[4+j] = e1[j]; ev[8+j] = e2[j]; ev[12+j] = e3[j]; }

    float* ob = out + O1 + n * (DIM * HW) + hw0 + lane;
    #pragma unroll
    for (int j = 0; j < 16; ++j) ob[(cg * 16 + j) * HW] = ev[j];    // coalesced planes
}

__global__ void k2a(const float* __restrict__ ema_cs, float* __restrict__ out,
                    const float* __restrict__ wsf) {
    __shared__ float s1[512], s2[512], s3[512];
    const int t = threadIdx.x;
    float c   = wsf[WS_CNT + t];
    float raw = 0.99f * ema_cs[t] + 0.01f * c;
    float p   = c * (1.0f / 65536.0f);
    s1[t] = raw;
    s2[t] = p * logf(p + 1e-10f);
    s3[t] = wsf[WS_LOSS + t];
    __syncthreads();
    for (int s = 256; s > 0; s >>= 1) {
        if (t < s) { s1[t] += s1[t + s]; s2[t] += s2[t + s]; s3[t] += s3[t + s]; }
        __syncthreads();
    }
    float n = s1[0];
    float smooth = (raw + 1e-5f) / (n + 512.0f * 1e-5f) * n;   // Laplace smoothing
    out[O4 + t] = smooth;
    if (t == 0) {
        out[O2] = expf(-s2[0]);
        out[O0] = 0.25f * s3[0] * (1.0f / 4194304.0f);         // BETA * mean
    }
}

__global__ void k2b(const float* __restrict__ ema_w, const float* __restrict__ wsf,
                    float* __restrict__ out) {
    const int m = blockIdx.x * 256 + threadIdx.x;   // 0..32767
    const int k = m >> 6;
    float w = 0.99f * ema_w[m] + 0.01f * wsf[WS_DW + m];
    out[O5 + m] = w;
    out[O6 + m] = w / out[O4 + k];                  // new_embedding = new_ema_w / new_cs
}

extern "C" void kernel_launch(void* const* d_in, const int* in_sizes, int n_in,
                              void* d_out, int out_size, void* d_ws, size_t ws_size,
                              hipStream_t stream) {
    const float* in     = (const float*)d_in[0];   // inputs  (64,64,32,32) NCHW
    const float* emb    = (const float*)d_in[1];   // embedding (512,64)
    const float* ema_w  = (const float*)d_in[2];   // ema_w (512,64)
    const float* ema_cs = (const float*)d_in[3];   // ema_cluster_size (512)
    float* out = (float*)d_out;
    float* wsf = (float*)d_ws;
    const int* idxw = (const int*)(wsf + WS_IDX);

    hipLaunchKernelGGL(k0_init, dim3(386),  dim3(256), 0, stream, emb, wsf);
    hipLaunchKernelGGL(k1_main, dim3(512),  dim3(512), 0, stream, in, emb, out, wsf);
    hipLaunchKernelGGL(k_dw,    dim3(512),  dim3(256), 0, stream, out + O1, idxw, wsf);
    hipLaunchKernelGGL(k_q,     dim3(1024), dim3(256), 0, stream, emb, idxw, out);
    hipLaunchKernelGGL(k2a,     dim3(1),    dim3(512), 0, stream, ema_cs, out, wsf);
    hipLaunchKernelGGL(k2b,     dim3(128),  dim3(256), 0, stream, ema_w, wsf, out);
}

// Round 5
// 181.879 us; speedup vs baseline: 1.6906x; 1.6906x over previous
//
#include <hip/hip_runtime.h>

#define K_CODES 512
#define DIM 64
#define HW 1024
#define NVEC 65536

// Output offsets (flat concat, reference return order)
#define O0 0             // loss (1)
#define O1 1             // out_q NCHW (4194304) -- used as dw-partial scratch until k_q
#define O2 4194305       // perplexity (1)
#define O3 4194306       // idx as float (65536)
#define O4 4259842       // new_cs (512)
#define O5 4260354       // new_ema_w (32768)
#define O6 4293122       // new_embedding (32768)

// ws float-offset layout (~600 KB)
#define WS_LOSS 0        // 512 per-block loss partials
#define WS_EE   1024     // 512 ||e||^2
#define WS_IDX  1536     // 65536 int idx
#define WS_PCNT 67072    // 64*512 int partial counts
#define WS_BP   99840    // 98304 bf16 B-pack (MFMA-frag order)
#define XSS     65       // odd LDS row stride -> <=2-way bank aliasing

#define NDWBLK  64       // dw-partial blocks (one image each)

typedef __bf16 bf16x8 __attribute__((ext_vector_type(8)));
typedef float  f32x4  __attribute__((ext_vector_type(4)));

__global__ void k0_init(const float* __restrict__ emb, float* __restrict__ wsf) {
    const int b = blockIdx.x, t = threadIdx.x;
    if (b < 2) {
        int k = b * 256 + t;                             // 0..511
        const float* e = emb + k * DIM;
        float s = 0.0f;
        #pragma unroll
        for (int c = 0; c < DIM; ++c) s += e[c] * e[c];
        wsf[WS_EE + k] = s;                              // ||e_k||^2
    } else {
        // Pack bf16 3-way split of (-2*e) into MFMA B-fragment order:
        // frag(s, ntg, ks): lane l holds B^T[code = ntg*16 + (l&15)][c = ks*32 + (l>>4)*8 + j]
        int g = (b - 2) * 256 + t;                       // 0..98303
        int j    = g & 7;
        int lane = (g >> 3) & 63;
        int ks   = (g >> 9) & 1;
        int rest = g >> 10;                              // 0..95
        int ntg  = rest & 31;
        int s    = rest >> 5;                            // split 0..2
        int code = ntg * 16 + (lane & 15);
        int c    = ks * 32 + (lane >> 4) * 8 + j;
        float v = -2.0f * emb[code * DIM + c];
        __bf16 h0 = (__bf16)v;  float r1 = v  - (float)h0;
        __bf16 h1 = (__bf16)r1; float r2 = r1 - (float)h1;
        __bf16 hv = (s == 0) ? h0 : (s == 1 ? h1 : (__bf16)r2);
        ((__bf16*)(wsf + WS_BP))[g] = hv;
    }
}

// Block: 512 threads = 8 waves; 128 vectors x 512 codes per block. GEMM + argmin only.
__global__ __launch_bounds__(512, 2)
void k1_main(const float* __restrict__ in, const float* __restrict__ emb,
             float* __restrict__ out, float* __restrict__ wsf) {
    __shared__ float xs[128 * XSS];
    __shared__ float pmin[4][128];
    __shared__ int   pidx[4][128];
    __shared__ float xxs[128];
    __shared__ float lossp[2];

    const int t    = threadIdx.x;
    const int lane = t & 63;
    const int wave = t >> 6;
    const int mi2  = wave & 1;         // m half (64 vectors)
    const int ni2  = wave >> 1;        // n quarter (128 codes)
    const int col  = lane & 15;
    const int quad = lane >> 4;

    const int blk     = blockIdx.x;
    const int n_img   = blk >> 3;
    const int hw_base = (blk & 7) * 128;
    const float* xbase = in + n_img * (DIM * HW) + hw_base;

    #pragma unroll
    for (int rep = 0; rep < 16; ++rep) {
        int e = rep * 512 + t;
        int c = e >> 7, h0 = e & 127;
        xs[h0 * XSS + c] = xbase[c * HW + h0];
    }

    f32x4 acc[4][8];
    #pragma unroll
    for (int nt = 0; nt < 8; ++nt) {
        float eev = wsf[WS_EE + ni2 * 128 + nt * 16 + col];
        #pragma unroll
        for (int mi = 0; mi < 4; ++mi) {
            acc[mi][nt][0] = eev; acc[mi][nt][1] = eev;
            acc[mi][nt][2] = eev; acc[mi][nt][3] = eev;
        }
    }

    __syncthreads();

    if (t < 128) {
        float s = 0.0f;
        #pragma unroll
        for (int c = 0; c < DIM; ++c) { float v = xs[t * XSS + c]; s += v * v; }
        xxs[t] = s;
    }

    const bf16x8* bp8 = (const bf16x8*)(wsf + WS_BP);

    #pragma unroll
    for (int ks = 0; ks < 2; ++ks) {
        bf16x8 A0[4], A1[4], A2[4];
        #pragma unroll
        for (int mi = 0; mi < 4; ++mi) {
            const float* src = &xs[(mi2 * 64 + mi * 16 + col) * XSS + ks * 32 + quad * 8];
            #pragma unroll
            for (int j = 0; j < 8; ++j) {
                float v = src[j];
                __bf16 h0 = (__bf16)v;  float r1 = v  - (float)h0;
                __bf16 h1 = (__bf16)r1; float r2 = r1 - (float)h1;
                A0[mi][j] = h0; A1[mi][j] = h1; A2[mi][j] = (__bf16)r2;
            }
        }
        #pragma unroll
        for (int s = 0; s < 3; ++s) {
            bf16x8 Bv[8];
            #pragma unroll
            for (int nt = 0; nt < 8; ++nt)
                Bv[nt] = bp8[(((s * 32 + ni2 * 8 + nt) * 2 + ks) * 64) + lane];
            #pragma unroll
            for (int mi = 0; mi < 4; ++mi)
                #pragma unroll
                for (int nt = 0; nt < 8; ++nt)
                    acc[mi][nt] = __builtin_amdgcn_mfma_f32_16x16x32_bf16(A0[mi], Bv[nt], acc[mi][nt], 0, 0, 0);
            if (s < 2) {
                #pragma unroll
                for (int mi = 0; mi < 4; ++mi)
                    #pragma unroll
                    for (int nt = 0; nt < 8; ++nt)
                        acc[mi][nt] = __builtin_amdgcn_mfma_f32_16x16x32_bf16(A1[mi], Bv[nt], acc[mi][nt], 0, 0, 0);
            }
            if (s == 0) {
                #pragma unroll
                for (int mi = 0; mi < 4; ++mi)
                    #pragma unroll
                    for (int nt = 0; nt < 8; ++nt)
                        acc[mi][nt] = __builtin_amdgcn_mfma_f32_16x16x32_bf16(A2[mi], Bv[nt], acc[mi][nt], 0, 0, 0);
            }
        }
    }

    // Argmin. C layout: col(code) = lane&15, row(vector) = quad*4 + reg.
    #pragma unroll
    for (int mi = 0; mi < 4; ++mi) {
        #pragma unroll
        for (int r = 0; r < 4; ++r) {
            float v  = acc[mi][0][r];
            int   bi = ni2 * 128 + col;
            #pragma unroll
            for (int nt = 1; nt < 8; ++nt) {            // ascending codes, strict < = first-min
                float u  = acc[mi][nt][r];
                int   ui = ni2 * 128 + nt * 16 + col;
                if (u < v) { v = u; bi = ui; }
            }
            #pragma unroll
            for (int off = 1; off < 16; off <<= 1) {    // 16-lane butterfly, idx tie-break
                float ov = __shfl_xor(v, off);
                int   oi = __shfl_xor(bi, off);
                if (ov < v || (ov == v && oi < bi)) { v = ov; bi = oi; }
            }
            if (col == 0) {
                int row = mi2 * 64 + mi * 16 + quad * 4 + r;
                pmin[ni2][row] = v;
                pidx[ni2][row] = bi;
            }
        }
    }
    __syncthreads();

    if (t < 128) {
        float v = pmin[0][t]; int bi = pidx[0][t];
        #pragma unroll
        for (int q = 1; q < 4; ++q) {
            float u = pmin[q][t]; int ui = pidx[q][t];
            if (u < v) { v = u; bi = ui; }
        }
        out[O3 + blk * 128 + t] = (float)bi;
        ((int*)(wsf + WS_IDX))[blk * 128 + t] = bi;
        float ld = v + xxs[t];                           // d_min = xx + (ee - 2<x,e>)
        #pragma unroll
        for (int off = 32; off > 0; off >>= 1) ld += __shfl_down(ld, off);
        if ((t & 63) == 0) lossp[t >> 6] = ld;
    }
    __syncthreads();
    if (t == 0) wsf[WS_LOSS + blk] = lossp[0] + lossp[1];
}

// dw via dense one-hot MFMA GEMM: block b owns image b (1024 vectors).
// partial dw [512 codes x 64 dims] -> pdw (O1 scratch); partial counts -> ws.
__global__ __launch_bounds__(512, 2)
void k_dw(const float* __restrict__ in, const int* __restrict__ idxw,
          float* __restrict__ pdw, int* __restrict__ pcnt) {
    __shared__ float xs[128 * XSS];
    __shared__ int   sidx[1024];
    __shared__ int   hist[K_CODES];

    const int t    = threadIdx.x;
    const int lane = t & 63;
    const int wave = t >> 6;           // 0..7: codes [wave*64, wave*64+64)
    const int col  = lane & 15;
    const int quad = lane >> 4;
    const int b    = blockIdx.x;       // image

    sidx[t]       = idxw[b * 1024 + t];
    sidx[t + 512] = idxw[b * 1024 + 512 + t];
    hist[t & 511] = 0;

    const float* xbase = in + b * (DIM * HW);

    f32x4 acc[4][4];                   // [mtile][ntile]: code=wave*64+mt*16+.., dim=nt*16+..
    #pragma unroll
    for (int mt = 0; mt < 4; ++mt)
        #pragma unroll
        for (int nt = 0; nt < 4; ++nt)
            acc[mt][nt] = (f32x4){0.f, 0.f, 0.f, 0.f};

    const __bf16 ONE = (__bf16)1.0f, ZERO = (__bf16)0.0f;

    for (int stage = 0; stage < 8; ++stage) {
        __syncthreads();
        #pragma unroll
        for (int rep = 0; rep < 16; ++rep) {
            int e = rep * 512 + t;
            int c = e >> 7, h0 = e & 127;
            xs[h0 * XSS + c] = xbase[c * HW + stage * 128 + h0];
        }
        __syncthreads();

        #pragma unroll
        for (int kstep = 0; kstep < 4; ++kstep) {
            const int kb = kstep * 32;
            // idx values for this quad's 8 k-slots (LDS broadcast reads)
            int iq[8];
            #pragma unroll
            for (int j = 0; j < 8; ++j) iq[j] = sidx[stage * 128 + kb + quad * 8 + j];

            // B frags: x[vec][dim] 3-way bf16 split from fp32 LDS
            bf16x8 B0[4], B1[4], B2[4];
            #pragma unroll
            for (int nt = 0; nt < 4; ++nt) {
                #pragma unroll
                for (int j = 0; j < 8; ++j) {
                    float v = xs[(kb + quad * 8 + j) * XSS + nt * 16 + col];
                    __bf16 h0 = (__bf16)v;  float r1 = v  - (float)h0;
                    __bf16 h1 = (__bf16)r1; float r2 = r1 - (float)h1;
                    B0[nt][j] = h0; B1[nt][j] = h1; B2[nt][j] = (__bf16)r2;
                }
            }
            // A frags: one-hot (exact in bf16); same A for all 3 splits
            #pragma unroll
            for (int mt = 0; mt < 4; ++mt) {
                const int code = wave * 64 + mt * 16 + col;
                bf16x8 A;
                #pragma unroll
                for (int j = 0; j < 8; ++j) A[j] = (iq[j] == code) ? ONE : ZERO;
                #pragma unroll
                for (int nt = 0; nt < 4; ++nt) {
                    acc[mt][nt] = __builtin_amdgcn_mfma_f32_16x16x32_bf16(A, B0[nt], acc[mt][nt], 0, 0, 0);
                    acc[mt][nt] = __builtin_amdgcn_mfma_f32_16x16x32_bf16(A, B1[nt], acc[mt][nt], 0, 0, 0);
                    acc[mt][nt] = __builtin_amdgcn_mfma_f32_16x16x32_bf16(A, B2[nt], acc[mt][nt], 0, 0, 0);
                }
            }
        }
    }

    // partial counts via LDS histogram
    atomicAdd(&hist[sidx[t]], 1);
    atomicAdd(&hist[sidx[t + 512]], 1);
    __syncthreads();
    pcnt[b * K_CODES + t] = hist[t];   // t < 512

    // partial dw store. C layout: row(code)=quad*4+reg, col(dim)=lane&15
    float* pb = pdw + b * (K_CODES * DIM);
    #pragma unroll
    for (int mt = 0; mt < 4; ++mt)
        #pragma unroll
        for (int nt = 0; nt < 4; ++nt)
            #pragma unroll
            for (int r = 0; r < 4; ++r)
                pb[(wave * 64 + mt * 16 + quad * 4 + r) * DIM + nt * 16 + col] = acc[mt][nt][r];
}

// Regenerate out_q into O1 from emb + idx (after k2b consumed the O1 scratch).
__global__ __launch_bounds__(256, 4)
void k_q(const float* __restrict__ emb, const int* __restrict__ idxw,
         float* __restrict__ out) {
    const int t    = threadIdx.x;
    const int lane = t & 63;
    const int cg   = t >> 6;                 // c-group 0..3 (16 channels each)
    const int b    = blockIdx.x;
    const int n    = b >> 4;
    const int hw0  = (b & 15) * 64;

    int iv = idxw[n * HW + hw0 + lane];
    const f32x4* er = (const f32x4*)(emb + iv * DIM + cg * 16);   // 64B row chunk
    f32x4 e0 = er[0], e1 = er[1], e2 = er[2], e3 = er[3];
    float ev[16];
    #pragma unroll
    for (int j = 0; j < 4; ++j) { ev[j] = e0[j]; ev[4+j] = e1[j]; ev[8+j] = e2[j]; ev[12+j] = e3[j]; }

    float* ob = out + O1 + n * (DIM * HW) + hw0 + lane;
    #pragma unroll
    for (int j = 0; j < 16; ++j) ob[(cg * 16 + j) * HW] = ev[j];    // coalesced planes
}

__global__ void k2a(const float* __restrict__ ema_cs, float* __restrict__ out,
                    const float* __restrict__ wsf) {
    __shared__ float s1[512], s2[512], s3[512];
    const int t = threadIdx.x;
    const int* pcnt = (const int*)(wsf + WS_PCNT);
    int ci = 0;
    #pragma unroll 8
    for (int g = 0; g < NDWBLK; ++g) ci += pcnt[g * K_CODES + t];  // coalesced columns
    float c   = (float)ci;
    float raw = 0.99f * ema_cs[t] + 0.01f * c;
    float p   = c * (1.0f / 65536.0f);
    s1[t] = raw;
    s2[t] = p * logf(p + 1e-10f);
    s3[t] = wsf[WS_LOSS + t];
    __syncthreads();
    for (int s = 256; s > 0; s >>= 1) {
        if (t < s) { s1[t] += s1[t + s]; s2[t] += s2[t + s]; s3[t] += s3[t + s]; }
        __syncthreads();
    }
    float n = s1[0];
    float smooth = (raw + 1e-5f) / (n + 512.0f * 1e-5f) * n;   // Laplace smoothing
    out[O4 + t] = smooth;
    if (t == 0) {
        out[O2] = expf(-s2[0]);
        out[O0] = 0.25f * s3[0] * (1.0f / 4194304.0f);         // BETA * mean
    }
}

// Reduce dw partials (from O1 scratch) + EMA weights + new embedding.
__global__ void k2b(const float* __restrict__ ema_w, const float* __restrict__ pdw,
                    float* __restrict__ out) {
    const int m = blockIdx.x * 256 + threadIdx.x;   // 0..32767
    const int k = m >> 6;
    float dw = 0.0f;
    #pragma unroll 8
    for (int g = 0; g < NDWBLK; ++g) dw += pdw[g * (K_CODES * DIM) + m];  // coalesced
    float w = 0.99f * ema_w[m] + 0.01f * dw;
    out[O5 + m] = w;
    out[O6 + m] = w / out[O4 + k];                  // new_embedding = new_ema_w / new_cs
}

extern "C" void kernel_launch(void* const* d_in, const int* in_sizes, int n_in,
                              void* d_out, int out_size, void* d_ws, size_t ws_size,
                              hipStream_t stream) {
    const float* in     = (const float*)d_in[0];   // inputs  (64,64,32,32) NCHW
    const float* emb    = (const float*)d_in[1];   // embedding (512,64)
    const float* ema_w  = (const float*)d_in[2];   // ema_w (512,64)
    const float* ema_cs = (const float*)d_in[3];   // ema_cluster_size (512)
    float* out = (float*)d_out;
    float* wsf = (float*)d_ws;
    const int* idxw = (const int*)(wsf + WS_IDX);
    float* pdw = out + O1;                          // O1 region as dw-partial scratch
    int*   pcnt = (int*)(wsf + WS_PCNT);

    hipLaunchKernelGGL(k0_init, dim3(386),    dim3(256), 0, stream, emb, wsf);
    hipLaunchKernelGGL(k1_main, dim3(512),    dim3(512), 0, stream, in, emb, out, wsf);
    hipLaunchKernelGGL(k_dw,    dim3(NDWBLK), dim3(512), 0, stream, in, idxw, pdw, pcnt);
    hipLaunchKernelGGL(k2a,     dim3(1),      dim3(512), 0, stream, ema_cs, out, wsf);
    hipLaunchKernelGGL(k2b,     dim3(128),    dim3(256), 0, stream, ema_w, pdw, out);
    hipLaunchKernelGGL(k_q,     dim3(1024),   dim3(256), 0, stream, emb, idxw, out);
}